// Round 6
// baseline (791.385 us; speedup 1.0000x reference)
//
#include <hip/hip_runtime.h>
#include <math.h>

#define N_NODES 8192
#define N_FEAT  256
#define N_EDGES 131072
#define N_DIR   (2*N_EDGES)

// ---------- helpers ----------

// directed edge k: s = ei[k]; d = ei[k<E ? k+E : k-E]
__device__ __forceinline__ void edge_sd(const int* __restrict__ ei, int k, int& s, int& d){
  s = ei[k];
  d = (k < N_EDGES) ? ei[k + N_EDGES] : ei[k - N_EDGES];
}

// device-coherent (L1-bypassing) label accesses — required for multi-block CC
__device__ __forceinline__ int aload(int* p){
  return __hip_atomic_load(p, __ATOMIC_RELAXED, __HIP_MEMORY_SCOPE_AGENT);
}
__device__ __forceinline__ void astore(int* p, int v){
  __hip_atomic_store(p, v, __ATOMIC_RELAXED, __HIP_MEMORY_SCOPE_AGENT);
}

// ---------- kernels ----------

// zero the full output buffer: 69.2M floats = 17.3M uint4
__global__ void k_zero(uint4* __restrict__ p, long long n4){
  long long i = (long long)blockIdx.x * blockDim.x + threadIdx.x;
  long long stride = (long long)gridDim.x * blockDim.x;
  uint4 z = {0u, 0u, 0u, 0u};
  for (; i < n4; i += stride) p[i] = z;
}

__global__ void k_init(int* __restrict__ cnt, int* __restrict__ deg,
                       int* __restrict__ np, int* __restrict__ label){
  int i = blockIdx.x * blockDim.x + threadIdx.x;
  if (i < N_NODES){ cnt[i] = 0; deg[i] = 0; label[i] = i; }
  if (i == 0) *np = 0;
}

// p1[i] = dot(x[i], w[:256]); p2[i] = dot(x[i], w[256:])  (f64 accumulate)
__global__ void k_proj(const float* __restrict__ x, const float* __restrict__ w,
                       float* __restrict__ p1, float* __restrict__ p2){
  int i = blockIdx.x;
  int t = threadIdx.x;                  // 256 threads
  float v = x[(size_t)i * N_FEAT + t];
  double a = (double)v * (double)w[t];
  double b = (double)v * (double)w[N_FEAT + t];
  for (int off = 32; off; off >>= 1){
    a += __shfl_down(a, off);
    b += __shfl_down(b, off);
  }
  __shared__ double sa[4], sb[4];
  int wid = t >> 6, lane = t & 63;
  if (lane == 0){ sa[wid] = a; sb[wid] = b; }
  __syncthreads();
  if (t == 0){
    p1[i] = (float)(sa[0] + sa[1] + sa[2] + sa[3]);
    p2[i] = (float)(sb[0] + sb[1] + sb[2] + sb[3]);
  }
}

// e per directed edge; count incoming non-self; contract degree; emit packed
// contract pairs via wave-aggregated compaction.
__global__ void k_edges(const int* __restrict__ ei, const float* __restrict__ p1,
                        const float* __restrict__ p2, const float* __restrict__ lb,
                        float* __restrict__ e_val, int* __restrict__ cnt,
                        int* __restrict__ deg, unsigned int* __restrict__ pairs,
                        int* __restrict__ np){
  int k = blockIdx.x * blockDim.x + threadIdx.x;
  int s, d; edge_sd(ei, k, s, d);
  bool selfe = (s == d);
  float e = 0.0f;
  if (!selfe){
    float z = p1[s] + p2[d] + lb[0];
    e = tanhf(z);
    e_val[k] = e;
    atomicAdd(&cnt[d], 1);
    if (e > 0.0f){
      atomicAdd(&deg[s], 1);
      atomicAdd(&deg[d], 1);
    }
  }
  bool c = (!selfe) && (e > 0.0f);
  unsigned long long m = __ballot(c);
  if (m){
    int lane = threadIdx.x & 63;
    int leader = __ffsll((unsigned long long)m) - 1;
    int base = 0;
    if (lane == leader) base = atomicAdd(np, __popcll(m));
    base = __shfl(base, leader);
    if (c){
      int prefix = __popcll(m & ((1ull << lane) - 1ull));
      pairs[base + prefix] = ((unsigned int)s << 13) | (unsigned int)d;
    }
  }
}

// exclusive scan of cnt[8192] -> row_start[8193], copy to cursor
__global__ void k_scan(const int* __restrict__ cnt, int* __restrict__ row_start,
                       int* __restrict__ cursor){
  __shared__ int wsum[1024];
  int t = threadIdx.x;                  // 1024 threads, 8 elems each
  int base = t * 8;
  int f[8]; int s = 0;
  #pragma unroll
  for (int j = 0; j < 8; ++j){ f[j] = cnt[base + j]; s += f[j]; }
  wsum[t] = s;
  __syncthreads();
  for (int off = 1; off < 1024; off <<= 1){
    int v = (t >= off) ? wsum[t - off] : 0;
    __syncthreads();
    wsum[t] += v;
    __syncthreads();
  }
  int run = wsum[t] - s;                // exclusive prefix for this chunk
  #pragma unroll
  for (int j = 0; j < 8; ++j){
    row_start[base + j] = run;
    cursor[base + j]    = run;
    run += f[j];
  }
  if (t == 1023) row_start[N_NODES] = run;
}

// CSR fill by destination
__global__ void k_fill(const int* __restrict__ ei, const float* __restrict__ e_val,
                       int* __restrict__ cursor, int* __restrict__ esrc, float* __restrict__ evs){
  int k = blockIdx.x * blockDim.x + threadIdx.x;
  if (k >= N_DIR) return;
  int s, d; edge_sd(ei, k, s, d);
  if (s == d) return;
  int slot = atomicAdd(&cursor[d], 1);
  esrc[slot] = s;
  evs[slot]  = e_val[k];
}

// Multi-block ECL-CC union over compacted contract pairs, global label array.
// All label accesses device-coherent; CAS-retry hooks (labels decrease
// monotonically -> livelock-free). Converged root == min node index.
__global__ void k_union_g(const unsigned int* __restrict__ pairs,
                          const int* __restrict__ np, int* __restrict__ label){
  int n = *np;
  int k = blockIdx.x * blockDim.x + threadIdx.x;
  int stride = gridDim.x * blockDim.x;
  for (; k < n; k += stride){
    unsigned int p = pairs[k];
    int s = (int)(p >> 13), d = (int)(p & 8191u);
    // fast path: equal current parents => already same component
    int ps = aload(&label[s]);
    int pd = aload(&label[d]);
    if (ps == pd) continue;
    // find roots with path compression
    int a = s, pa = ps;
    while (pa != a){
      int g = aload(&label[pa]);
      if (g != pa) astore(&label[a], g);
      a = pa; pa = g;
    }
    int b = d, pb = pd;
    while (pb != b){
      int g = aload(&label[pb]);
      if (g != pb) astore(&label[b], g);
      b = pb; pb = g;
    }
    while (a != b){
      if (a < b){ int t = a; a = b; b = t; }   // hook larger root a -> smaller b
      int ret = atomicCAS(&label[a], a, b);
      if (ret == a) break;                      // hooked
      a = ret;                                  // root moved; re-find both roots
      int q = aload(&label[a]);
      while (q != a){ a = q; q = aload(&label[a]); }
      int qb = aload(&label[b]);
      while (qb != b){ b = qb; qb = aload(&label[b]); }
    }
  }
}

// Single-WG finisher: copy labels to LDS, flatten, rank roots via scan,
// emit cluster ids + float outputs.
__global__ void __launch_bounds__(1024) k_rank(
    const int* __restrict__ labelG, const int* __restrict__ batch,
    int* __restrict__ cluster_i, float* __restrict__ out_cluster,
    float* __restrict__ out_batch){
  __shared__ int L[N_NODES];            // 32 KB
  __shared__ int wsum[1024];
  int t = threadIdx.x;
  for (int i = t; i < N_NODES; i += 1024) L[i] = labelG[i];
  __syncthreads();

  // flatten via read-only walks (post-union chains are stable & short)
  int base = t * 8;
  int l_reg[8];
  #pragma unroll
  for (int j = 0; j < 8; ++j){
    int l = L[base + j];
    while (true){ int q = L[l]; if (q == l) break; l = q; }
    l_reg[j] = l;
  }
  __syncthreads();

  // rank roots: flag + block-wide scan
  int f[8]; int s = 0;
  #pragma unroll
  for (int j = 0; j < 8; ++j){ f[j] = (l_reg[j] == base + j) ? 1 : 0; s += f[j]; }
  wsum[t] = s;
  __syncthreads();
  for (int off = 1; off < 1024; off <<= 1){
    int v = (t >= off) ? wsum[t - off] : 0;
    __syncthreads();
    wsum[t] += v;
    __syncthreads();
  }
  int run = wsum[t] - s;                // exclusive prefix
  #pragma unroll
  for (int j = 0; j < 8; ++j){
    run += f[j];
    if (f[j]) L[base + j] = run - 1;    // root slot <- cluster id
  }
  __syncthreads();

  #pragma unroll
  for (int j = 0; j < 8; ++j){
    int i = base + j;
    int c = L[l_reg[j]];
    cluster_i[i] = c;
    out_cluster[i] = (float)c;
    out_batch[c] = (float)batch[i];     // last-write-wins; batch uniform
  }
}

// y[i,:] = (isolated ? x[i,:] : 0) + sum_{edges s->i} e * x[s,:]
__global__ void k_y(const float* __restrict__ x, const float* __restrict__ evs,
                    const int* __restrict__ esrc, const int* __restrict__ row_start,
                    const int* __restrict__ deg, float* __restrict__ y){
  int i = blockIdx.x;
  int t = threadIdx.x;                  // 256 threads = feature dim
  int a = row_start[i], b = row_start[i + 1];
  float acc = (deg[i] == 0) ? x[(size_t)i * N_FEAT + t] : 0.0f;
  for (int j = a; j < b; ++j){
    acc += evs[j] * x[(size_t)esrc[j] * N_FEAT + t];
  }
  y[(size_t)i * N_FEAT + t] = acc;
}

// X_new[cluster[i],:] += y[i,:]  (run-length register accumulation, then atomicAdd)
__global__ void k_xnew(const float* __restrict__ y, const int* __restrict__ cluster_i,
                       float* __restrict__ Xn){
  int t = threadIdx.x;                  // 256 threads
  int node0 = blockIdx.x * 32;
  float acc = 0.0f;
  int cur = cluster_i[node0];
  for (int j = 0; j < 32; ++j){
    int node = node0 + j;
    int c = cluster_i[node];
    if (c != cur){
      atomicAdd(&Xn[(size_t)cur * N_FEAT + t], acc);
      acc = 0.0f; cur = c;
    }
    acc += y[(size_t)node * N_FEAT + t];
  }
  atomicAdd(&Xn[(size_t)cur * N_FEAT + t], acc);
}

// A_c[cs,cd] += 1 per directed non-self edge crossing clusters (diag zeroed by ref)
__global__ void k_ac(const int* __restrict__ ei, const int* __restrict__ cluster_i,
                     float* __restrict__ Ac){
  int k = blockIdx.x * blockDim.x + threadIdx.x;
  if (k >= N_DIR) return;
  int s, d; edge_sd(ei, k, s, d);
  if (s == d) return;
  int cs = cluster_i[s], cd = cluster_i[d];
  if (cs != cd) atomicAdd(&Ac[(size_t)cs * N_NODES + cd], 1.0f);
}

// ---------- launcher ----------

extern "C" void kernel_launch(void* const* d_in, const int* in_sizes, int n_in,
                              void* d_out, int out_size, void* d_ws, size_t ws_size,
                              hipStream_t stream){
  const float* x     = (const float*)d_in[0];
  const int*   ei    = (const int*)  d_in[1];
  const int*   batch = (const int*)  d_in[2];
  const float* lw    = (const float*)d_in[3];
  const float* lb    = (const float*)d_in[4];

  float* out = (float*)d_out;
  float* Xn  = out;                                       // 8192*256
  float* Ac  = Xn + (size_t)N_NODES * N_FEAT;             // 8192*8192
  float* ob  = Ac + (size_t)N_NODES * N_NODES;            // 8192 (new_batch)
  float* oc  = ob + N_NODES;                              // 8192 (cluster)

  char* w = (char*)d_ws;
  float* p1        = (float*)w; w += (size_t)N_NODES * 4;
  float* p2        = (float*)w; w += (size_t)N_NODES * 4;
  float* e_val     = (float*)w; w += (size_t)N_DIR   * 4;
  int*   cnt       = (int*)  w; w += (size_t)N_NODES * 4;
  int*   cursor    = (int*)  w; w += (size_t)N_NODES * 4;
  int*   row_start = (int*)  w; w += (size_t)(N_NODES + 8) * 4;
  int*   deg       = (int*)  w; w += (size_t)N_NODES * 4;
  int*   cluster_i = (int*)  w; w += (size_t)N_NODES * 4;
  int*   labelG    = (int*)  w; w += (size_t)N_NODES * 4;
  int*   esrc      = (int*)  w; w += (size_t)N_DIR   * 4;
  float* evs       = (float*)w; w += (size_t)N_DIR   * 4;
  unsigned int* pairs = (unsigned int*)w; w += (size_t)N_DIR * 4;
  int*   np        = (int*)  w; w += 64;
  float* y         = (float*)w; w += (size_t)N_NODES * N_FEAT * 4;

  // zero entire output (covers X_new, A_c, new_batch, cluster slots)
  long long n4 = (long long)out_size / 4;
  k_zero  <<<4096, 256, 0, stream>>>((uint4*)d_out, n4);

  k_init  <<<(N_NODES + 255) / 256, 256, 0, stream>>>(cnt, deg, np, labelG);
  k_proj  <<<N_NODES, 256, 0, stream>>>(x, lw, p1, p2);
  k_edges <<<N_DIR / 256, 256, 0, stream>>>(ei, p1, p2, lb, e_val, cnt, deg, pairs, np);
  k_scan  <<<1, 1024, 0, stream>>>(cnt, row_start, cursor);
  k_fill  <<<N_DIR / 256, 256, 0, stream>>>(ei, e_val, cursor, esrc, evs);
  k_union_g<<<1024, 256, 0, stream>>>(pairs, np, labelG);
  k_rank  <<<1, 1024, 0, stream>>>(labelG, batch, cluster_i, oc, ob);
  k_y     <<<N_NODES, 256, 0, stream>>>(x, evs, esrc, row_start, deg, y);
  k_xnew  <<<N_NODES / 32, 256, 0, stream>>>(y, cluster_i, Xn);
  k_ac    <<<N_DIR / 256, 256, 0, stream>>>(ei, cluster_i, Ac);
}

// Round 7
// 254.880 us; speedup vs baseline: 3.1049x; 3.1049x over previous
//
#include <hip/hip_runtime.h>
#include <math.h>

#define N_NODES 8192
#define N_FEAT  256
#define N_EDGES 131072
#define N_DIR   (2*N_EDGES)

// ---------- helpers ----------

// directed edge k: s = ei[k]; d = ei[k<E ? k+E : k-E]
__device__ __forceinline__ void edge_sd(const int* __restrict__ ei, int k, int& s, int& d){
  s = ei[k];
  d = (k < N_EDGES) ? ei[k + N_EDGES] : ei[k - N_EDGES];
}

// ECL-CC representative with path compression, LDS variant.
__device__ __forceinline__ int rep_lds(int v, int* L){
  int curr = L[v];
  if (curr != v){
    int prev = v, next;
    while (curr > (next = L[curr])){
      L[prev] = next;
      prev = curr;
      curr = next;
    }
  }
  return curr;
}

// ---------- kernels ----------

__global__ void k_init(int* __restrict__ cnt, int* __restrict__ deg, int* __restrict__ np){
  int i = blockIdx.x * blockDim.x + threadIdx.x;
  if (i < N_NODES){ cnt[i] = 0; deg[i] = 0; }
  if (i == 0) *np = 0;
}

// p1[i] = dot(x[i], w[:256]); p2[i] = dot(x[i], w[256:])  (f64 accumulate)
__global__ void k_proj(const float* __restrict__ x, const float* __restrict__ w,
                       float* __restrict__ p1, float* __restrict__ p2){
  int i = blockIdx.x;
  int t = threadIdx.x;                  // 256 threads
  float v = x[(size_t)i * N_FEAT + t];
  double a = (double)v * (double)w[t];
  double b = (double)v * (double)w[N_FEAT + t];
  for (int off = 32; off; off >>= 1){
    a += __shfl_down(a, off);
    b += __shfl_down(b, off);
  }
  __shared__ double sa[4], sb[4];
  int wid = t >> 6, lane = t & 63;
  if (lane == 0){ sa[wid] = a; sb[wid] = b; }
  __syncthreads();
  if (t == 0){
    p1[i] = (float)(sa[0] + sa[1] + sa[2] + sa[3]);
    p2[i] = (float)(sb[0] + sb[1] + sb[2] + sb[3]);
  }
}

// e per directed edge; count incoming non-self; contract degree; emit packed
// contract pairs via wave-aggregated compaction.
__global__ void k_edges(const int* __restrict__ ei, const float* __restrict__ p1,
                        const float* __restrict__ p2, const float* __restrict__ lb,
                        float* __restrict__ e_val, int* __restrict__ cnt,
                        int* __restrict__ deg, unsigned int* __restrict__ pairs,
                        int* __restrict__ np){
  int k = blockIdx.x * blockDim.x + threadIdx.x;
  int s, d; edge_sd(ei, k, s, d);
  bool selfe = (s == d);
  float e = 0.0f;
  if (!selfe){
    float z = p1[s] + p2[d] + lb[0];
    e = tanhf(z);
    e_val[k] = e;
    atomicAdd(&cnt[d], 1);
    if (e > 0.0f){
      atomicAdd(&deg[s], 1);
      atomicAdd(&deg[d], 1);
    }
  }
  bool c = (!selfe) && (e > 0.0f);
  unsigned long long m = __ballot(c);
  if (m){
    int lane = threadIdx.x & 63;
    int leader = __ffsll((unsigned long long)m) - 1;
    int base = 0;
    if (lane == leader) base = atomicAdd(np, __popcll(m));
    base = __shfl(base, leader);
    if (c){
      int prefix = __popcll(m & ((1ull << lane) - 1ull));
      pairs[base + prefix] = ((unsigned int)s << 13) | (unsigned int)d;
    }
  }
}

// exclusive scan of cnt[8192] -> row_start[8193], copy to cursor
__global__ void k_scan(const int* __restrict__ cnt, int* __restrict__ row_start,
                       int* __restrict__ cursor){
  __shared__ int wsum[1024];
  int t = threadIdx.x;                  // 1024 threads, 8 elems each
  int base = t * 8;
  int f[8]; int s = 0;
  #pragma unroll
  for (int j = 0; j < 8; ++j){ f[j] = cnt[base + j]; s += f[j]; }
  wsum[t] = s;
  __syncthreads();
  for (int off = 1; off < 1024; off <<= 1){
    int v = (t >= off) ? wsum[t - off] : 0;
    __syncthreads();
    wsum[t] += v;
    __syncthreads();
  }
  int run = wsum[t] - s;                // exclusive prefix for this chunk
  #pragma unroll
  for (int j = 0; j < 8; ++j){
    row_start[base + j] = run;
    cursor[base + j]    = run;
    run += f[j];
  }
  if (t == 1023) row_start[N_NODES] = run;
}

// CSR fill by destination
__global__ void k_fill(const int* __restrict__ ei, const float* __restrict__ e_val,
                       int* __restrict__ cursor, int* __restrict__ esrc, float* __restrict__ evs){
  int k = blockIdx.x * blockDim.x + threadIdx.x;
  if (k >= N_DIR) return;
  int s, d; edge_sd(ei, k, s, d);
  if (s == d) return;
  int slot = atomicAdd(&cursor[d], 1);
  esrc[slot] = s;
  evs[slot]  = e_val[k];
}

// FUSED: block 0 = connected components in LDS (chunked ECL-CC + rank + emit);
// blocks 1..  = zero X_new and A_c (69.2M - 16K floats) with uint4 stores.
// Data-disjoint: block 0 owns out_batch/out_cluster slots and zeroes ob itself.
__global__ void __launch_bounds__(1024) k_fused(
    const unsigned int* __restrict__ pairs, const int* __restrict__ np,
    const int* __restrict__ batch,
    int* __restrict__ cluster_i, float* __restrict__ out_cluster,
    float* __restrict__ out_batch,
    uint4* __restrict__ zbase, long long n4){
  int t = threadIdx.x;

  if (blockIdx.x != 0){
    long long i = (long long)(blockIdx.x - 1) * blockDim.x + t;
    long long stride = (long long)(gridDim.x - 1) * blockDim.x;
    uint4 z = {0u, 0u, 0u, 0u};
    for (; i < n4; i += stride) zbase[i] = z;
    return;
  }

  // ---- block 0: CC ----
  __shared__ int L[N_NODES];            // 32 KB parent array
  __shared__ int wsum[1024];            // 4 KB scan buffer

  for (int i = t; i < N_NODES; i += 1024) L[i] = i;
  // zero new_batch slots (overlaps with LDS init; no dependency)
  for (int i = t; i < N_NODES; i += 1024) out_batch[i] = 0.0f;
  __syncthreads();

  int n = *np;
  const int CH = 16384;
  for (int cbase = 0; cbase < n; cbase += CH){
    int lim = (cbase + CH < n) ? (cbase + CH) : n;
    for (int k = cbase + t; k < lim; k += 1024){
      unsigned int p = pairs[k];
      int s = (int)(p >> 13), d = (int)(p & 8191u);
      int a = L[s], b = L[d];
      if (a == b) continue;             // fast path: already same component
      a = rep_lds(s, L);
      b = rep_lds(d, L);
      bool repeat;
      do {
        repeat = false;
        if (a != b){
          int ret;
          if (a < b){
            if ((ret = atomicCAS(&L[b], b, a)) != b){ b = ret; repeat = true; }
          } else {
            if ((ret = atomicCAS(&L[a], a, b)) != a){ a = ret; repeat = true; }
          }
        }
      } while (repeat);
    }
    __syncthreads();
    // full flatten (plain stores; safe between barriers)
    for (int i = t; i < N_NODES; i += 1024){
      int l = L[i];
      while (true){ int q = L[l]; if (q == l) break; l = q; }
      L[i] = l;
    }
    __syncthreads();
  }

  // L[i] is now the min-label root for every node
  int base = t * 8;
  int l_reg[8];
  #pragma unroll
  for (int j = 0; j < 8; ++j) l_reg[j] = L[base + j];
  __syncthreads();

  // rank roots: flag + block-wide scan (1024 threads x 8)
  int f[8]; int s = 0;
  #pragma unroll
  for (int j = 0; j < 8; ++j){ f[j] = (l_reg[j] == base + j) ? 1 : 0; s += f[j]; }
  wsum[t] = s;
  __syncthreads();
  for (int off = 1; off < 1024; off <<= 1){
    int v = (t >= off) ? wsum[t - off] : 0;
    __syncthreads();
    wsum[t] += v;
    __syncthreads();
  }
  int run = wsum[t] - s;                // exclusive prefix
  #pragma unroll
  for (int j = 0; j < 8; ++j){
    run += f[j];
    if (f[j]) L[base + j] = run - 1;    // root slot <- cluster id
  }
  __syncthreads();

  #pragma unroll
  for (int j = 0; j < 8; ++j){
    int i = base + j;
    int c = L[l_reg[j]];
    cluster_i[i] = c;
    out_cluster[i] = (float)c;
    out_batch[c] = (float)batch[i];     // last-write-wins; batch uniform
  }
}

// y[i,:] = (isolated ? x[i,:] : 0) + sum_{edges s->i} e * x[s,:]
__global__ void k_y(const float* __restrict__ x, const float* __restrict__ evs,
                    const int* __restrict__ esrc, const int* __restrict__ row_start,
                    const int* __restrict__ deg, float* __restrict__ y){
  int i = blockIdx.x;
  int t = threadIdx.x;                  // 256 threads = feature dim
  int a = row_start[i], b = row_start[i + 1];
  float acc = (deg[i] == 0) ? x[(size_t)i * N_FEAT + t] : 0.0f;
  for (int j = a; j < b; ++j){
    acc += evs[j] * x[(size_t)esrc[j] * N_FEAT + t];
  }
  y[(size_t)i * N_FEAT + t] = acc;
}

// X_new[cluster[i],:] += y[i,:]  (run-length register accumulation, then atomicAdd)
__global__ void k_xnew(const float* __restrict__ y, const int* __restrict__ cluster_i,
                       float* __restrict__ Xn){
  int t = threadIdx.x;                  // 256 threads
  int node0 = blockIdx.x * 32;
  float acc = 0.0f;
  int cur = cluster_i[node0];
  for (int j = 0; j < 32; ++j){
    int node = node0 + j;
    int c = cluster_i[node];
    if (c != cur){
      atomicAdd(&Xn[(size_t)cur * N_FEAT + t], acc);
      acc = 0.0f; cur = c;
    }
    acc += y[(size_t)node * N_FEAT + t];
  }
  atomicAdd(&Xn[(size_t)cur * N_FEAT + t], acc);
}

// A_c[cs,cd] += 1 per directed non-self edge crossing clusters (diag zeroed by ref)
__global__ void k_ac(const int* __restrict__ ei, const int* __restrict__ cluster_i,
                     float* __restrict__ Ac){
  int k = blockIdx.x * blockDim.x + threadIdx.x;
  if (k >= N_DIR) return;
  int s, d; edge_sd(ei, k, s, d);
  if (s == d) return;
  int cs = cluster_i[s], cd = cluster_i[d];
  if (cs != cd) atomicAdd(&Ac[(size_t)cs * N_NODES + cd], 1.0f);
}

// ---------- launcher ----------

extern "C" void kernel_launch(void* const* d_in, const int* in_sizes, int n_in,
                              void* d_out, int out_size, void* d_ws, size_t ws_size,
                              hipStream_t stream){
  const float* x     = (const float*)d_in[0];
  const int*   ei    = (const int*)  d_in[1];
  const int*   batch = (const int*)  d_in[2];
  const float* lw    = (const float*)d_in[3];
  const float* lb    = (const float*)d_in[4];

  float* out = (float*)d_out;
  float* Xn  = out;                                       // 8192*256
  float* Ac  = Xn + (size_t)N_NODES * N_FEAT;             // 8192*8192
  float* ob  = Ac + (size_t)N_NODES * N_NODES;            // 8192 (new_batch)
  float* oc  = ob + N_NODES;                              // 8192 (cluster)

  char* w = (char*)d_ws;
  float* p1        = (float*)w; w += (size_t)N_NODES * 4;
  float* p2        = (float*)w; w += (size_t)N_NODES * 4;
  float* e_val     = (float*)w; w += (size_t)N_DIR   * 4;
  int*   cnt       = (int*)  w; w += (size_t)N_NODES * 4;
  int*   cursor    = (int*)  w; w += (size_t)N_NODES * 4;
  int*   row_start = (int*)  w; w += (size_t)(N_NODES + 8) * 4;
  int*   deg       = (int*)  w; w += (size_t)N_NODES * 4;
  int*   cluster_i = (int*)  w; w += (size_t)N_NODES * 4;
  int*   esrc      = (int*)  w; w += (size_t)N_DIR   * 4;
  float* evs       = (float*)w; w += (size_t)N_DIR   * 4;
  unsigned int* pairs = (unsigned int*)w; w += (size_t)N_DIR * 4;
  int*   np        = (int*)  w; w += 64;
  float* y         = (float*)w; w += (size_t)N_NODES * N_FEAT * 4;

  // Xn + Ac region to zero (new_batch/cluster handled by fused block 0)
  long long n4 = ((long long)N_NODES * N_FEAT + (long long)N_NODES * N_NODES) / 4;

  k_init  <<<(N_NODES + 255) / 256, 256, 0, stream>>>(cnt, deg, np);
  k_proj  <<<N_NODES, 256, 0, stream>>>(x, lw, p1, p2);
  k_edges <<<N_DIR / 256, 256, 0, stream>>>(ei, p1, p2, lb, e_val, cnt, deg, pairs, np);
  k_scan  <<<1, 1024, 0, stream>>>(cnt, row_start, cursor);
  k_fill  <<<N_DIR / 256, 256, 0, stream>>>(ei, e_val, cursor, esrc, evs);
  k_fused <<<1025, 1024, 0, stream>>>(pairs, np, batch, cluster_i, oc, ob,
                                      (uint4*)out, n4);
  k_y     <<<N_NODES, 256, 0, stream>>>(x, evs, esrc, row_start, deg, y);
  k_xnew  <<<N_NODES / 32, 256, 0, stream>>>(y, cluster_i, Xn);
  k_ac    <<<N_DIR / 256, 256, 0, stream>>>(ei, cluster_i, Ac);
}